// Round 6
// baseline (5969.601 us; speedup 1.0000x reference)
//
#include <hip/hip_runtime.h>

// ===========================================================================
// R6 = R2-EXACT real path (adaptive strip fp32 pipeline, passed at 5933us)
//      + tiny-scale (16-row) suspect-kernel diagnostics confined to d_out,
//      run BEFORE the real path (which then fully overwrites d_out).
// ===========================================================================

using bf16x8 = __attribute__((ext_vector_type(8))) short;
using f32x4  = __attribute__((ext_vector_type(4))) float;

__device__ __forceinline__ ushort f2bf(float f) {
  uint u = __float_as_uint(f);
  u = (u + 0x7fffu + ((u >> 16) & 1u)) >> 16;   // RNE
  return (ushort)u;
}
__device__ __forceinline__ uint pack2(float a, float b) {
  return (uint)f2bf(a) | ((uint)f2bf(b) << 16);
}

// ---------------------------------------------------------------------------
// [R2 VERBATIM] Generalized direct 3x3 SAME conv + ReLU, fp32, row-range.
// ---------------------------------------------------------------------------
template<int CIN, int COUT, int CB>
__global__ __launch_bounds__(256) void conv3x3_relu_k(
    const float* __restrict__ in, const float* __restrict__ wt,
    float* __restrict__ out,
    int W, int in_y0, int in_rows, int out_y0, int out_rows)
{
  constexpr int NCB = (COUT + CB - 1) / CB;
  const int n   = blockIdx.z / NCB;
  const int co0 = (blockIdx.z % NCB) * CB;
  const int tx = threadIdx.x & 15, ty = threadIdx.x >> 4;
  const int x0 = blockIdx.x * 16;
  const int oy0 = out_y0 + blockIdx.y * 16;
  const int x = x0 + tx;

  __shared__ float tile[18][19];

  float acc[CB];
#pragma unroll
  for (int j = 0; j < CB; ++j) acc[j] = 0.f;

  const float* inN = in + (size_t)n * CIN * in_rows * W;

  for (int ci = 0; ci < CIN; ++ci) {
    const float* ip = inN + (size_t)ci * in_rows * W;
    for (int t = threadIdx.x; t < 18 * 18; t += 256) {
      int r = t / 18, c = t - r * 18;
      int yi = oy0 + r - 1 - in_y0;
      int xi = x0 + c - 1;
      float v = 0.f;
      if (yi >= 0 && yi < in_rows && xi >= 0 && xi < W)
        v = ip[(size_t)yi * W + xi];
      tile[r][c] = v;
    }
    __syncthreads();

    const float p0 = tile[ty + 0][tx + 0], p1 = tile[ty + 0][tx + 1], p2 = tile[ty + 0][tx + 2];
    const float p3 = tile[ty + 1][tx + 0], p4 = tile[ty + 1][tx + 1], p5 = tile[ty + 1][tx + 2];
    const float p6 = tile[ty + 2][tx + 0], p7 = tile[ty + 2][tx + 1], p8 = tile[ty + 2][tx + 2];

#pragma unroll
    for (int j = 0; j < CB; ++j) {
      int co = co0 + j;
      if (co >= COUT) co = COUT - 1;
      const float* wp = wt + ((size_t)co * CIN + ci) * 9;
      float a = acc[j];
      a = fmaf(p0, wp[0], a); a = fmaf(p1, wp[1], a); a = fmaf(p2, wp[2], a);
      a = fmaf(p3, wp[3], a); a = fmaf(p4, wp[4], a); a = fmaf(p5, wp[5], a);
      a = fmaf(p6, wp[6], a); a = fmaf(p7, wp[7], a); a = fmaf(p8, wp[8], a);
      acc[j] = a;
    }
    __syncthreads();
  }

  const int orow = (oy0 + ty) - out_y0;
  float* outN = out + (size_t)n * COUT * out_rows * W;
  if (orow < out_rows) {
#pragma unroll
    for (int j = 0; j < CB; ++j) {
      int co = co0 + j;
      if (co < COUT) {
        float v = acc[j] < 0.f ? 0.f : acc[j];
        outN[((size_t)co * out_rows + orow) * W + x] = v;
      }
    }
  }
}

// ---------------------------------------------------------------------------
// [R2 VERBATIM] PixelShuffle r=4 + ReLU, one image.
// ---------------------------------------------------------------------------
__global__ __launch_bounds__(256) void pixel_shuffle_relu_k(
    const float* __restrict__ in, float* __restrict__ out)
{
  int i = blockIdx.x * 256 + threadIdx.x;
  int x = i & 1023, y = i >> 10;
  int c = (y & 3) * 4 + (x & 3);
  float v = in[((size_t)c * 256 + (y >> 2)) * 256 + (x >> 2)];
  out[i] = v < 0.f ? 0.f : v;
}

// ---------------------------------------------------------------------------
// [R2 VERBATIM] Per-pixel 5x5 dynamic conv + residual, planar ker strip.
// ---------------------------------------------------------------------------
__global__ __launch_bounds__(256) void pixel_conv_add_k(
    const float* __restrict__ h, const float* __restrict__ ker,
    float* __restrict__ out, int ky0, int krows)
{
  const int tx = threadIdx.x & 15, ty = threadIdx.x >> 4;
  const int x0 = blockIdx.x * 16;
  const int y0 = ky0 + blockIdx.y * 16;

  __shared__ float tile[20][21];
  for (int t = threadIdx.x; t < 20 * 20; t += 256) {
    int r = t / 20, c = t - r * 20;
    int yy = y0 + r - 2, xx = x0 + c - 2;
    float v = 0.f;
    if (yy >= 0 && yy < 1024 && xx >= 0 && xx < 1024) v = h[(size_t)yy * 1024 + xx];
    tile[r][c] = v;
  }
  __syncthreads();

  const int x = x0 + tx, y = y0 + ty;
  float acc = tile[ty + 2][tx + 2];
  const size_t kpix = (size_t)(y - ky0) * 1024 + x;
#pragma unroll
  for (int kw = 0; kw < 5; ++kw)
#pragma unroll
    for (int kh = 0; kh < 5; ++kh) {
      float kv = ker[(size_t)(kw * 5 + kh) * krows * 1024 + kpix];
      acc = fmaf(tile[ty + kh][tx + kw], kv, acc);
    }
  out[(size_t)y * 1024 + x] = acc;
}

// ===========================================================================
// SUSPECT KERNELS (R4 verbatim) — tiny-scale dead compute in d_out.
// ===========================================================================

__global__ __launch_bounds__(256) void wprep_k(
    const float* __restrict__ w, ushort* __restrict__ Wt,
    int COUT, int CIN, int COPAD)
{
  const int WROW = CIN + 8;
  int idx = blockIdx.x * 256 + threadIdx.x;
  int total = 9 * COPAD * WROW;
  if (idx >= total) return;
  int tap = idx / (COPAD * WROW);
  int r = idx - tap * (COPAD * WROW);
  int co = r / WROW, ci = r - co * WROW;
  float v = 0.f;
  if (co < COUT && ci < CIN) v = w[((size_t)co * CIN + ci) * 9 + tap];
  Wt[idx] = f2bf(v);
}

__global__ __launch_bounds__(256) void conv1to32_k(
    const float* __restrict__ h, const float* __restrict__ w,
    ushort* __restrict__ X1)
{
  const int tx = threadIdx.x & 15, ty = threadIdx.x >> 4;
  const int x0 = blockIdx.x * 16, y0 = blockIdx.y * 16;

  __shared__ float tile[18][19];
  for (int t = threadIdx.x; t < 18 * 18; t += 256) {
    int r = t / 18, c = t - r * 18;
    int yy = y0 + r - 1, xx = x0 + c - 1;
    float v = 0.f;
    if (yy >= 0 && yy < 1024 && xx >= 0 && xx < 1024) v = h[(size_t)yy * 1024 + xx];
    tile[r][c] = v;
  }
  __syncthreads();

  float p[9];
#pragma unroll
  for (int ky = 0; ky < 3; ++ky)
#pragma unroll
    for (int kx = 0; kx < 3; ++kx) p[ky * 3 + kx] = tile[ty + ky][tx + kx];

  uint pk[16];
#pragma unroll
  for (int cp = 0; cp < 16; ++cp) {
    float a0 = 0.f, a1 = 0.f;
    const float* w0 = w + (size_t)(2 * cp) * 9;
    const float* w1 = w0 + 9;
#pragma unroll
    for (int t = 0; t < 9; ++t) { a0 = fmaf(p[t], w0[t], a0); a1 = fmaf(p[t], w1[t], a1); }
    a0 = a0 < 0.f ? 0.f : a0;  a1 = a1 < 0.f ? 0.f : a1;
    pk[cp] = pack2(a0, a1);
  }

  uint4* op = (uint4*)(X1 + ((size_t)(y0 + ty + 1) * 1026 + (x0 + tx + 1)) * 32);
  op[0] = make_uint4(pk[0], pk[1], pk[2], pk[3]);
  op[1] = make_uint4(pk[4], pk[5], pk[6], pk[7]);
  op[2] = make_uint4(pk[8], pk[9], pk[10], pk[11]);
  op[3] = make_uint4(pk[12], pk[13], pk[14], pk[15]);
}

template<int CIN, int COPAD, int COUT, bool F32OUT>
__global__ __launch_bounds__(256) void conv_mfma_k(
    const ushort* __restrict__ Xin, const ushort* __restrict__ Wt,
    void* __restrict__ Out)
{
  constexpr int KC = CIN / 32, NC = COPAD / 16, WROW = CIN + 8;
  constexpr int Wp = 1026;

  __shared__ __align__(16) ushort wlds[9 * COPAD * WROW];
  {
    const uint4* src = (const uint4*)Wt;
    uint4* dst = (uint4*)wlds;
    const int n16 = 9 * COPAD * WROW * 2 / 16;
    for (int i = threadIdx.x; i < n16; i += 256) dst[i] = src[i];
  }
  __syncthreads();

  const int wave = threadIdx.x >> 6, lane = threadIdx.x & 63;
  const int grp = lane >> 4, pq = lane & 15;
  const int y  = blockIdx.y;
  const int xw = blockIdx.x * 256 + wave * 64;

  f32x4 acc[4][NC];
#pragma unroll
  for (int p = 0; p < 4; ++p)
#pragma unroll
    for (int ct = 0; ct < NC; ++ct) acc[p][ct] = (f32x4){0.f, 0.f, 0.f, 0.f};

#pragma unroll
  for (int ky = 0; ky < 3; ++ky) {
#pragma unroll
    for (int kx = 0; kx < 3; ++kx) {
      const int tap = ky * 3 + kx;
      bf16x8 a[NC][KC];
#pragma unroll
      for (int ct = 0; ct < NC; ++ct)
#pragma unroll
        for (int c = 0; c < KC; ++c)
          a[ct][c] = *(const bf16x8*)&wlds[(size_t)(tap * COPAD + ct * 16 + pq) * WROW + c * 32 + grp * 8];

      const ushort* xrow = Xin + ((size_t)(y + ky) * Wp + (xw + pq + kx)) * CIN + grp * 8;
#pragma unroll
      for (int p = 0; p < 4; ++p) {
        bf16x8 b[KC];
#pragma unroll
        for (int c = 0; c < KC; ++c)
          b[c] = *(const bf16x8*)(xrow + (size_t)p * 16 * CIN + c * 32);
#pragma unroll
        for (int ct = 0; ct < NC; ++ct)
#pragma unroll
          for (int c = 0; c < KC; ++c)
            acc[p][ct] = __builtin_amdgcn_mfma_f32_16x16x32_bf16(a[ct][c], b[c], acc[p][ct], 0, 0, 0);
      }
    }
  }

  if (!F32OUT) {
    ushort* OutU = (ushort*)Out;
#pragma unroll
    for (int p = 0; p < 4; ++p) {
      const size_t pix = (size_t)(y + 1) * Wp + (xw + p * 16 + pq + 1);
      ushort* op = OutU + pix * COPAD;
#pragma unroll
      for (int ct = 0; ct < NC; ++ct) {
        f32x4 v = acc[p][ct];
        float v0 = v[0] < 0.f ? 0.f : v[0];
        float v1 = v[1] < 0.f ? 0.f : v[1];
        float v2 = v[2] < 0.f ? 0.f : v[2];
        float v3 = v[3] < 0.f ? 0.f : v[3];
        uint2 pk2; pk2.x = pack2(v0, v1); pk2.y = pack2(v2, v3);
        *(uint2*)(op + ct * 16 + grp * 4) = pk2;
      }
    }
  } else {
    float* OutF = (float*)Out;
#pragma unroll
    for (int p = 0; p < 4; ++p) {
      float* op = OutF + ((size_t)y * 1024 + (xw + p * 16 + pq)) * 28;
#pragma unroll
      for (int ct = 0; ct < NC; ++ct) {
        const int co0 = ct * 16 + grp * 4;
        f32x4 v = acc[p][ct];
        float v0 = v[0] < 0.f ? 0.f : v[0];
        float v1 = v[1] < 0.f ? 0.f : v[1];
        float v2 = v[2] < 0.f ? 0.f : v[2];
        float v3 = v[3] < 0.f ? 0.f : v[3];
        if (co0 + 3 < COUT) {
          f32x4 s = {v0, v1, v2, v3};
          *(f32x4*)(op + co0) = s;
        } else if (co0 < COUT) {
          op[co0] = v0;
        }
      }
    }
  }
}

__global__ __launch_bounds__(256) void pixel_conv_add2_k(
    const float* __restrict__ h, const float* __restrict__ ker,
    float* __restrict__ out)
{
  const int tx = threadIdx.x & 15, ty = threadIdx.x >> 4;
  const int x0 = blockIdx.x * 16, y0 = blockIdx.y * 16;

  __shared__ float tile[20][21];
  for (int t = threadIdx.x; t < 20 * 20; t += 256) {
    int r = t / 20, c = t - r * 20;
    int yy = y0 + r - 2, xx = x0 + c - 2;
    float v = 0.f;
    if (yy >= 0 && yy < 1024 && xx >= 0 && xx < 1024) v = h[(size_t)yy * 1024 + xx];
    tile[r][c] = v;
  }
  __syncthreads();

  const int x = x0 + tx, y = y0 + ty;
  const float* kp = ker + ((size_t)y * 1024 + x) * 28;
  f32x4 kvv[7];
#pragma unroll
  for (int i = 0; i < 7; ++i) kvv[i] = *(const f32x4*)(kp + 4 * i);

  float acc = tile[ty + 2][tx + 2];
#pragma unroll
  for (int kw = 0; kw < 5; ++kw)
#pragma unroll
    for (int kh = 0; kh < 5; ++kh) {
      const int j = kw * 5 + kh;
      acc = fmaf(tile[ty + kh][tx + kw], kvv[j >> 2][j & 3], acc);
    }

  out[(size_t)y * 1024 + x] = acc;
}

// ---------------------------------------------------------------------------
// Launch: tiny diagnostics in d_out first, then R2-EXACT pipeline.
//
// Diag layout inside d_out (8,388,608 B; fully overwritten by real path):
//  Wt2d  @ 0         :    46,080
//  Wt3d  @ 46,080    :    41,472
//  Wt4d  @ 87,552    :    23,040
//  X1t   @ 110,592   : 1,181,952  (18 x 1026 x 32 bf16)
//  X2t   @ 1,292,544 : 2,363,904  (18 x 1026 x 64 bf16)
//  K4ot  @ 3,656,448 : 1,835,008  (16 x 1024 x 28 fp32)
//  Pt    @ 5,491,456 :    65,536  (16 x 1024 fp32)          end 5,556,992
// ---------------------------------------------------------------------------
extern "C" void kernel_launch(void* const* d_in, const int* in_sizes, int n_in,
                              void* d_out, int out_size, void* d_ws, size_t ws_size,
                              hipStream_t stream) {
  const float* x    = (const float*)d_in[0];
  const float* w_e1 = (const float*)d_in[1];
  const float* w_e2 = (const float*)d_in[2];
  const float* w_e3 = (const float*)d_in[3];
  const float* w_d1 = (const float*)d_in[4];
  const float* w_d2 = (const float*)d_in[5];
  const float* w_k1 = (const float*)d_in[6];
  const float* w_k2 = (const float*)d_in[7];
  const float* w_k3 = (const float*)d_in[8];
  const float* w_k4 = (const float*)d_in[9];

  dim3 blk(256);

  // ==================== DIAGNOSTICS (tiny, in d_out) =======================
  {
    char* ob = (char*)d_out;
    ushort* Wt2d = (ushort*)(ob + 0);
    ushort* Wt3d = (ushort*)(ob + 46080);
    ushort* Wt4d = (ushort*)(ob + 87552);
    ushort* X1t  = (ushort*)(ob + 110592);
    ushort* X2t  = (ushort*)(ob + 1292544);
    float*  K4ot = (float*) (ob + 3656448);
    float*  Pt   = (float*) (ob + 5491456);
    float*  Hsp  = (float*)d_ws;  // poison-read source (harmless, deterministic)

    wprep_k<<<dim3((9 * 64 * 40 + 255) / 256), blk, 0, stream>>>(w_k2, Wt2d, 64, 32, 64);
    wprep_k<<<dim3((9 * 32 * 72 + 255) / 256), blk, 0, stream>>>(w_k3, Wt3d, 32, 64, 32);
    wprep_k<<<dim3((9 * 32 * 40 + 255) / 256), blk, 0, stream>>>(w_k4, Wt4d, 25, 32, 32);
    conv1to32_k<<<dim3(64, 1), blk, 0, stream>>>(Hsp, w_k1, X1t);
    conv_mfma_k<32, 64, 64, false><<<dim3(4, 16), blk, 0, stream>>>(X1t, Wt2d, X2t);
    conv_mfma_k<64, 32, 32, false><<<dim3(4, 16), blk, 0, stream>>>(X2t, Wt3d, X1t);
    conv_mfma_k<32, 32, 25, true ><<<dim3(4, 16), blk, 0, stream>>>(X1t, Wt4d, K4ot);
    pixel_conv_add2_k<<<dim3(64, 1), blk, 0, stream>>>(Hsp, K4ot, Pt);
  }

  // ==================== REAL PATH (R2 EXACT) ===============================
  const size_t HS_SZ = 8388608;
  const size_t AMIN  = 8388608;
  const size_t BMIN  = 16777216;

  int S = 64;
  {
    const int cand[5] = {1024, 512, 256, 128, 64};
    for (int i = 0; i < 5; ++i) {
      int s = cand[i];
      size_t a = 32ull * (size_t)(s + 6) * 1024 * 4; if (a < AMIN) a = AMIN;
      size_t b = 64ull * (size_t)(s + 4) * 1024 * 4; if (b < BMIN) b = BMIN;
      if (HS_SZ + a + b <= ws_size) { S = s; break; }
    }
  }
  size_t A_SZ = 32ull * (size_t)(S + 6) * 1024 * 4; if (A_SZ < AMIN) A_SZ = AMIN;

  char* ws = (char*)d_ws;
  float* Hs = (float*)(ws);
  float* A  = (float*)(ws + HS_SZ);
  float* B  = (float*)(ws + HS_SZ + A_SZ);
  float* outp = (float*)d_out;

  for (int n = 0; n < 2; ++n) {
    const float* xn = x + (size_t)n * 65536;
    conv3x3_relu_k<1, 16, 16><<<dim3(16, 16, 1), blk, 0, stream>>>(xn, w_e1, B, 256, 0, 256, 0, 256);
    conv3x3_relu_k<16, 32, 16><<<dim3(16, 16, 2), blk, 0, stream>>>(B, w_e2, A, 256, 0, 256, 0, 256);
    conv3x3_relu_k<32, 64, 16><<<dim3(16, 16, 4), blk, 0, stream>>>(A, w_e3, B, 256, 0, 256, 0, 256);
    conv3x3_relu_k<64, 32, 16><<<dim3(16, 16, 2), blk, 0, stream>>>(B, w_d1, A, 256, 0, 256, 0, 256);
    conv3x3_relu_k<32, 16, 16><<<dim3(16, 16, 1), blk, 0, stream>>>(A, w_d2, B, 256, 0, 256, 0, 256);
    pixel_shuffle_relu_k<<<dim3(4096), blk, 0, stream>>>(B, Hs + (size_t)n * 1048576);
  }

  const int nstr = 1024 / S;
  for (int n = 0; n < 2; ++n) {
    const float* himg = Hs + (size_t)n * 1048576;
    float* outn = outp + (size_t)n * 1048576;
    for (int s = 0; s < nstr; ++s) {
      const int r0 = s * S, r1 = r0 + S;
      const int z1y0 = (r0 - 3 > 0) ? r0 - 3 : 0;
      const int z1r  = ((r1 + 3 < 1024) ? r1 + 3 : 1024) - z1y0;
      const int z2y0 = (r0 - 2 > 0) ? r0 - 2 : 0;
      const int z2r  = ((r1 + 2 < 1024) ? r1 + 2 : 1024) - z2y0;
      const int z3y0 = (r0 - 1 > 0) ? r0 - 1 : 0;
      const int z3r  = ((r1 + 1 < 1024) ? r1 + 1 : 1024) - z3y0;
      const int g1 = (z1r + 15) / 16, g2 = (z2r + 15) / 16, g3 = (z3r + 15) / 16;

      conv3x3_relu_k<1, 32, 16><<<dim3(64, g1, 2), blk, 0, stream>>>(
          himg, w_k1, A, 1024, 0, 1024, z1y0, z1r);
      conv3x3_relu_k<32, 64, 16><<<dim3(64, g2, 4), blk, 0, stream>>>(
          A, w_k2, B, 1024, z1y0, z1r, z2y0, z2r);
      conv3x3_relu_k<64, 32, 16><<<dim3(64, g3, 2), blk, 0, stream>>>(
          B, w_k3, A, 1024, z2y0, z2r, z3y0, z3r);
      conv3x3_relu_k<32, 25, 16><<<dim3(64, S / 16, 2), blk, 0, stream>>>(
          A, w_k4, B, 1024, z3y0, z3r, r0, S);
      pixel_conv_add_k<<<dim3(64, S / 16), blk, 0, stream>>>(
          himg, B, outn, r0, S);
    }
  }
}